// Round 1
// baseline (289.720 us; speedup 1.0000x reference)
//
#include <hip/hip_runtime.h>
#include <math.h>

// Problem constants (from reference): B=2, L=5, C=32, H=48, W=176, NUM_ITER=1.
// Key algebraic cuts:
//  - output only needs feat[:,0] after 1 iter -> only i=0 slice of (i,j) pairs.
//  - conv(cat(warped, ego)) = conv_w(warped) + conv_e(ego); ego half shared over j.
#define BB 2
#define LL 5
#define CC 32
#define HH 48
#define WW 176
#define HWs (HH * WW)          // 8448
#define BL (BB * LL)           // 10

// ---- bilinear weights/indices for grid_sample(align_corners=False, zeros pad) ----
__device__ __forceinline__ void bilin_weights(const float* __restrict__ Mp, int h, int w,
                                              int& o00, int& o10, int& o01, int& o11,
                                              float& a00, float& a10, float& a01, float& a11)
{
    float xs = (2.0f * (float)w + 1.0f) / (float)WW - 1.0f;
    float ys = (2.0f * (float)h + 1.0f) / (float)HH - 1.0f;
    float gx = Mp[0] * xs + Mp[1] * ys + Mp[2];
    float gy = Mp[3] * xs + Mp[4] * ys + Mp[5];
    float ix = ((gx + 1.0f) * (float)WW - 1.0f) * 0.5f;
    float iy = ((gy + 1.0f) * (float)HH - 1.0f) * 0.5f;
    float x0f = floorf(ix), y0f = floorf(iy);
    float wx = ix - x0f, wy = iy - y0f;
    float x1f = x0f + 1.0f, y1f = y0f + 1.0f;
    bool vx0 = (x0f >= 0.0f) && (x0f <= (float)(WW - 1));
    bool vx1 = (x1f >= 0.0f) && (x1f <= (float)(WW - 1));
    bool vy0 = (y0f >= 0.0f) && (y0f <= (float)(HH - 1));
    bool vy1 = (y1f >= 0.0f) && (y1f <= (float)(HH - 1));
    int xi0 = (int)fminf(fmaxf(x0f, 0.0f), (float)(WW - 1));
    int xi1 = (int)fminf(fmaxf(x1f, 0.0f), (float)(WW - 1));
    int yi0 = (int)fminf(fmaxf(y0f, 0.0f), (float)(HH - 1));
    int yi1 = (int)fminf(fmaxf(y1f, 0.0f), (float)(HH - 1));
    o00 = yi0 * WW + xi0;
    o10 = yi0 * WW + xi1;
    o01 = yi1 * WW + xi0;
    o11 = yi1 * WW + xi1;
    a00 = (vx0 && vy0) ? (1.0f - wx) * (1.0f - wy) : 0.0f;
    a10 = (vx1 && vy0) ? wx * (1.0f - wy) : 0.0f;
    a01 = (vx0 && vy1) ? (1.0f - wx) * wy : 0.0f;
    a11 = (vx1 && vy1) ? wx * wy : 0.0f;
}

// ---- K1: warped[b,j,c,h,w] = bilinear(feat[b,j], grid(M[b,0,j])) ----
__global__ __launch_bounds__(256) void k_warp(const float* __restrict__ x,
                                              const float* __restrict__ M,
                                              float* __restrict__ warped)
{
    int idx = blockIdx.x * 256 + threadIdx.x;
    if (idx >= BL * HWs) return;
    int w = idx % WW;
    int h = (idx / WW) % HH;
    int bj = idx / HWs;           // = b*L + j
    int b = bj / LL, j = bj % LL;
    const float* Mp = M + (size_t)(b * LL * LL + j) * 6;   // M[b][0][j]

    int o00, o10, o01, o11;
    float a00, a10, a01, a11;
    bilin_weights(Mp, h, w, o00, o10, o01, o11, a00, a10, a01, a11);

    const float* img = x + (size_t)bj * CC * HWs;          // feat[b][j]
    float* wp = warped + (size_t)bj * CC * HWs + h * WW + w;
#pragma unroll 4
    for (int c = 0; c < CC; ++c) {
        const float* ip = img + c * HWs;
        float v = a00 * ip[o00] + a10 * ip[o10] + a01 * ip[o01] + a11 * ip[o11];
        wp[(size_t)c * HWs] = v;
    }
}

// ---- K2: half-convs. jobs 0..9: warped half (ic 0..31); jobs 10..11: ego half (ic 32..63) ----
__global__ __launch_bounds__(256) void k_conv(const float* __restrict__ x,
                                              const float* __restrict__ warped,
                                              const float* __restrict__ msg_w,
                                              float* __restrict__ msgpart,
                                              float* __restrict__ econv)
{
    int job = blockIdx.y;
    int pix = blockIdx.x * 256 + threadIdx.x;
    if (pix >= HWs) return;
    int w = pix % WW, h = pix / WW;

    const float* img;
    const float* wt;
    float* outp;
    if (job < BL) {
        img  = warped + (size_t)job * CC * HWs;
        wt   = msg_w;                 // ic 0..31
        outp = msgpart + (size_t)job * CC * HWs;
    } else {
        int b = job - BL;
        img  = x + (size_t)(b * LL) * CC * HWs;  // feat[b][0]
        wt   = msg_w + 32 * 9;        // ic offset 32 (stride 9 per ic)
        outp = econv + (size_t)b * CC * HWs;
    }

    float acc[CC];
#pragma unroll
    for (int oc = 0; oc < CC; ++oc) acc[oc] = 0.0f;

    for (int ic = 0; ic < 32; ++ic) {
        const float* ip = img + (size_t)ic * HWs;
        float v[9];
#pragma unroll
        for (int ky = 0; ky < 3; ++ky) {
#pragma unroll
            for (int kx = 0; kx < 3; ++kx) {
                int hh = h + ky - 1, ww = w + kx - 1;
                v[ky * 3 + kx] = (hh >= 0 && hh < HH && ww >= 0 && ww < WW) ? ip[hh * WW + ww] : 0.0f;
            }
        }
        const float* wp = wt + ic * 9;    // msg_w[oc][ic][ky][kx], oc stride = 64*9 = 576
#pragma unroll 8
        for (int oc = 0; oc < CC; ++oc) {
            const float* wq = wp + oc * 576;
            float s = acc[oc];
#pragma unroll
            for (int k = 0; k < 9; ++k) s += v[k] * wq[k];
            acc[oc] = s;
        }
    }
#pragma unroll 4
    for (int oc = 0; oc < CC; ++oc) outp[(size_t)oc * HWs + pix] = acc[oc];
}

// ---- K3: agg = max_j (msgpart_j + econv + bias) * mask_j ; out = mlp(x0 + agg) ----
__global__ __launch_bounds__(256) void k_combine(const float* __restrict__ x,
                                                 const float* __restrict__ M,
                                                 const float* __restrict__ msgpart,
                                                 const float* __restrict__ econv,
                                                 const float* __restrict__ msg_b,
                                                 const float* __restrict__ mlp_w,
                                                 const float* __restrict__ mlp_b,
                                                 float* __restrict__ out)
{
    int b = blockIdx.y;
    int pix = blockIdx.x * 256 + threadIdx.x;
    if (pix >= HWs) return;
    int w = pix % WW, h = pix / WW;

    float ec[CC];
#pragma unroll 4
    for (int c = 0; c < CC; ++c)
        ec[c] = econv[(size_t)(b * CC + c) * HWs + pix] + msg_b[c];

    float agg[CC];
#pragma unroll
    for (int c = 0; c < CC; ++c) agg[c] = -INFINITY;

    for (int j = 0; j < LL; ++j) {
        const float* Mp = M + (size_t)(b * LL * LL + j) * 6;
        int o00, o10, o01, o11;
        float a00, a10, a01, a11;
        bilin_weights(Mp, h, w, o00, o10, o01, o11, a00, a10, a01, a11);
        float m = a00 + a10 + a01 + a11;   // grid_sample of ones image

        const float* mp = msgpart + (size_t)(b * LL + j) * CC * HWs + pix;
#pragma unroll 4
        for (int c = 0; c < CC; ++c) {
            float val = (mp[(size_t)c * HWs] + ec[c]) * m;
            agg[c] = fmaxf(agg[c], val);
        }
    }

    const float* x0 = x + (size_t)(b * LL) * CC * HWs + pix;   // feat[b][0]
    float f[CC];
#pragma unroll 4
    for (int c = 0; c < CC; ++c) f[c] = x0[(size_t)c * HWs] + agg[c];

#pragma unroll 2
    for (int d = 0; d < CC; ++d) {
        float s = mlp_b[d];
        const float* wr = mlp_w + d * CC;
#pragma unroll
        for (int c = 0; c < CC; ++c) s += f[c] * wr[c];
        out[(size_t)(b * CC + d) * HWs + pix] = s;
    }
}

extern "C" void kernel_launch(void* const* d_in, const int* in_sizes, int n_in,
                              void* d_out, int out_size, void* d_ws, size_t ws_size,
                              hipStream_t stream)
{
    (void)in_sizes; (void)n_in; (void)out_size; (void)ws_size;
    const float* x     = (const float*)d_in[0];
    // d_in[1] = record_len (unused by reference)
    const float* M     = (const float*)d_in[2];
    const float* msg_w = (const float*)d_in[3];
    const float* msg_b = (const float*)d_in[4];
    const float* mlp_w = (const float*)d_in[5];
    const float* mlp_b = (const float*)d_in[6];
    float* out = (float*)d_out;

    float* ws      = (float*)d_ws;
    float* warped  = ws;                               // BL*C*HW = 2,703,360 floats
    float* msgpart = warped + (size_t)BL * CC * HWs;   // 2,703,360 floats
    float* econv   = msgpart + (size_t)BL * CC * HWs;  // BB*C*HW = 540,672 floats
    // total ws use: ~23.8 MB

    {
        int total = BL * HWs;
        dim3 g((total + 255) / 256);
        k_warp<<<g, 256, 0, stream>>>(x, M, warped);
    }
    {
        dim3 g((HWs + 255) / 256, BL + BB);  // 12 jobs
        k_conv<<<g, 256, 0, stream>>>(x, warped, msg_w, msgpart, econv);
    }
    {
        dim3 g((HWs + 255) / 256, BB);
        k_combine<<<g, 256, 0, stream>>>(x, M, msgpart, econv, msg_b, mlp_w, mlp_b, out);
    }
}

// Round 2
// 87.903 us; speedup vs baseline: 3.2959x; 3.2959x over previous
//
#include <hip/hip_runtime.h>
#include <math.h>

// B=2, L=5, C=32, H=48, W=176, NUM_ITER=1.
// Algebraic cuts (validated round 1): only i=0 slice matters; conv split into
// warped-half (per j) + ego-half (per b, shared over j).
#define BB 2
#define LL 5
#define CC 32
#define HH 48
#define WW 176
#define HWs (HH * WW)          // 8448
#define BL (BB * LL)           // 10
#define PPT 4                  // pixels per thread in k_conv

// ---- bilinear weights/indices for grid_sample(align_corners=False, zeros pad) ----
__device__ __forceinline__ void bilin_weights(const float* __restrict__ Mp, int h, int w,
                                              int& o00, int& o10, int& o01, int& o11,
                                              float& a00, float& a10, float& a01, float& a11)
{
    float xs = (2.0f * (float)w + 1.0f) / (float)WW - 1.0f;
    float ys = (2.0f * (float)h + 1.0f) / (float)HH - 1.0f;
    float gx = Mp[0] * xs + Mp[1] * ys + Mp[2];
    float gy = Mp[3] * xs + Mp[4] * ys + Mp[5];
    float ix = ((gx + 1.0f) * (float)WW - 1.0f) * 0.5f;
    float iy = ((gy + 1.0f) * (float)HH - 1.0f) * 0.5f;
    float x0f = floorf(ix), y0f = floorf(iy);
    float wx = ix - x0f, wy = iy - y0f;
    float x1f = x0f + 1.0f, y1f = y0f + 1.0f;
    bool vx0 = (x0f >= 0.0f) && (x0f <= (float)(WW - 1));
    bool vx1 = (x1f >= 0.0f) && (x1f <= (float)(WW - 1));
    bool vy0 = (y0f >= 0.0f) && (y0f <= (float)(HH - 1));
    bool vy1 = (y1f >= 0.0f) && (y1f <= (float)(HH - 1));
    int xi0 = (int)fminf(fmaxf(x0f, 0.0f), (float)(WW - 1));
    int xi1 = (int)fminf(fmaxf(x1f, 0.0f), (float)(WW - 1));
    int yi0 = (int)fminf(fmaxf(y0f, 0.0f), (float)(HH - 1));
    int yi1 = (int)fminf(fmaxf(y1f, 0.0f), (float)(HH - 1));
    o00 = yi0 * WW + xi0;
    o10 = yi0 * WW + xi1;
    o01 = yi1 * WW + xi0;
    o11 = yi1 * WW + xi1;
    a00 = (vx0 && vy0) ? (1.0f - wx) * (1.0f - wy) : 0.0f;
    a10 = (vx1 && vy0) ? wx * (1.0f - wy) : 0.0f;
    a01 = (vx0 && vy1) ? (1.0f - wx) * wy : 0.0f;
    a11 = (vx1 && vy1) ? wx * wy : 0.0f;
}

// ---- K1: warped[bj][c][pix] = bilinear(feat[b,j], grid(M[b,0,j])); c split 4-way ----
__global__ __launch_bounds__(256) void k_warp(const float* __restrict__ x,
                                              const float* __restrict__ M,
                                              float* __restrict__ warped)
{
    int pix = blockIdx.x * 256 + threadIdx.x;
    if (pix >= HWs) return;
    int bj = blockIdx.y;
    int cg = blockIdx.z;
    int w = pix % WW, h = pix / WW;
    int b = bj / LL, j = bj % LL;
    const float* Mp = M + (size_t)(b * LL * LL + j) * 6;   // M[b][0][j]

    int o00, o10, o01, o11;
    float a00, a10, a01, a11;
    bilin_weights(Mp, h, w, o00, o10, o01, o11, a00, a10, a01, a11);

    const float* img = x + (size_t)bj * CC * HWs + (size_t)cg * 8 * HWs;
    float* wp = warped + (size_t)bj * CC * HWs + (size_t)cg * 8 * HWs + pix;
#pragma unroll
    for (int c = 0; c < 8; ++c) {
        const float* ip = img + (size_t)c * HWs;
        float v = a00 * ip[o00] + a10 * ip[o10] + a01 * ip[o01] + a11 * ip[o11];
        wp[(size_t)c * HWs] = v;
    }
}

// ---- K2: half-convs. jobs 0..9: warped half; jobs 10..11: ego half ----
// Output layouts: msgpart[job][pix][c], econv[b][pix][c]  (for float4 reads in K3)
__global__ __launch_bounds__(256) void k_conv(const float* __restrict__ x,
                                              const float* __restrict__ warped,
                                              const float* __restrict__ msg_w,
                                              float* __restrict__ msgpart,
                                              float* __restrict__ econv)
{
    __shared__ alignas(16) float wlds[32 * 72];   // [ic][oc 8][9]
    int job = blockIdx.y;
    int grp = blockIdx.z;       // oc group: oc = grp*8 + 0..7
    int icbase = (job < BL) ? 0 : 32;

    // stage weight slice: 2304 floats, 9 per thread
    for (int i = threadIdx.x; i < 32 * 72; i += 256) {
        int ic = i / 72, r = i % 72, oc = r / 9, k = r % 9;
        wlds[i] = msg_w[(size_t)(grp * 8 + oc) * 576 + (size_t)(icbase + ic) * 9 + k];
    }
    __syncthreads();

    int p0 = blockIdx.x * (256 * PPT) + threadIdx.x * PPT;
    if (p0 >= HWs) return;
    int w0 = p0 % WW;           // multiple of 4 (176 % 4 == 0) -> float4 aligned
    int h  = p0 / WW;

    const float* img;
    float* outp;
    if (job < BL) {
        img  = warped + (size_t)job * CC * HWs;
        outp = msgpart + (size_t)job * HWs * CC;
    } else {
        int b = job - BL;
        img  = x + (size_t)(b * LL) * CC * HWs;  // feat[b][0]
        outp = econv + (size_t)b * HWs * CC;
    }

    float acc[8][PPT];
#pragma unroll
    for (int oc = 0; oc < 8; ++oc)
#pragma unroll
        for (int p = 0; p < PPT; ++p) acc[oc][p] = 0.0f;

    for (int ic = 0; ic < 32; ++ic) {
        const float* ip = img + (size_t)ic * HWs;
        // rows h-1..h+1, cols w0-1..w0+4
        float row[3][6];
#pragma unroll
        for (int r = 0; r < 3; ++r) {
            int hh = h - 1 + r;
            bool hok = (hh >= 0) && (hh < HH);
            const float* bp = ip + hh * WW + w0;
            float4 mid = hok ? *(const float4*)bp : make_float4(0.f, 0.f, 0.f, 0.f);
            row[r][1] = mid.x; row[r][2] = mid.y; row[r][3] = mid.z; row[r][4] = mid.w;
            row[r][0] = (hok && w0 > 0)        ? bp[-1] : 0.0f;
            row[r][5] = (hok && w0 + 4 < WW)   ? bp[4]  : 0.0f;
        }
        // prefetch this ic's 72 weights into registers (vectorizable b128 broadcasts)
        float Wf[72];
#pragma unroll
        for (int i = 0; i < 72; ++i) Wf[i] = wlds[ic * 72 + i];

#pragma unroll
        for (int oc = 0; oc < 8; ++oc)
#pragma unroll
            for (int ky = 0; ky < 3; ++ky)
#pragma unroll
                for (int kx = 0; kx < 3; ++kx) {
                    float wv = Wf[oc * 9 + ky * 3 + kx];
#pragma unroll
                    for (int p = 0; p < PPT; ++p)
                        acc[oc][p] = fmaf(row[ky][p + kx], wv, acc[oc][p]);
                }
    }

#pragma unroll
    for (int p = 0; p < PPT; ++p) {
        float4 lo = make_float4(acc[0][p], acc[1][p], acc[2][p], acc[3][p]);
        float4 hi = make_float4(acc[4][p], acc[5][p], acc[6][p], acc[7][p]);
        float* op = outp + (size_t)(p0 + p) * CC + grp * 8;
        *(float4*)op       = lo;
        *(float4*)(op + 4) = hi;
    }
}

// ---- K3: agg = max_j (msgpart_j + econv + bias) * mask_j ; out = mlp(x0 + agg); d split 4-way ----
__global__ __launch_bounds__(256) void k_combine(const float* __restrict__ x,
                                                 const float* __restrict__ M,
                                                 const float* __restrict__ msgpart,
                                                 const float* __restrict__ econv,
                                                 const float* __restrict__ msg_b,
                                                 const float* __restrict__ mlp_w,
                                                 const float* __restrict__ mlp_b,
                                                 float* __restrict__ out)
{
    __shared__ alignas(16) float wl[8 * 32];   // mlp_w rows dg*8..dg*8+7
    __shared__ float bl[8];
    __shared__ float mb[32];
    int b  = blockIdx.y;
    int dg = blockIdx.z;
    {
        int t = threadIdx.x;
        if (t < 256) wl[t] = mlp_w[(size_t)(dg * 8 + t / 32) * 32 + (t % 32)];
        if (t < 8)   bl[t] = mlp_b[dg * 8 + t];
        if (t < 32)  mb[t] = msg_b[t];
    }
    __syncthreads();

    int pix = blockIdx.x * 256 + threadIdx.x;
    if (pix >= HWs) return;
    int w = pix % WW, h = pix / WW;

    float ec[CC];
    {
        const float4* ep = (const float4*)(econv + ((size_t)b * HWs + pix) * CC);
#pragma unroll
        for (int q = 0; q < 8; ++q) {
            float4 v = ep[q];
            ec[4 * q + 0] = v.x + mb[4 * q + 0];
            ec[4 * q + 1] = v.y + mb[4 * q + 1];
            ec[4 * q + 2] = v.z + mb[4 * q + 2];
            ec[4 * q + 3] = v.w + mb[4 * q + 3];
        }
    }

    float agg[CC];
#pragma unroll
    for (int c = 0; c < CC; ++c) agg[c] = -INFINITY;

    for (int j = 0; j < LL; ++j) {
        const float* Mp = M + (size_t)(b * LL * LL + j) * 6;
        int o00, o10, o01, o11;
        float a00, a10, a01, a11;
        bilin_weights(Mp, h, w, o00, o10, o01, o11, a00, a10, a01, a11);
        float m = a00 + a10 + a01 + a11;   // grid_sample of ones image

        const float4* mp = (const float4*)(msgpart + ((size_t)(b * LL + j) * HWs + pix) * CC);
#pragma unroll
        for (int q = 0; q < 8; ++q) {
            float4 v = mp[q];
            agg[4 * q + 0] = fmaxf(agg[4 * q + 0], (v.x + ec[4 * q + 0]) * m);
            agg[4 * q + 1] = fmaxf(agg[4 * q + 1], (v.y + ec[4 * q + 1]) * m);
            agg[4 * q + 2] = fmaxf(agg[4 * q + 2], (v.z + ec[4 * q + 2]) * m);
            agg[4 * q + 3] = fmaxf(agg[4 * q + 3], (v.w + ec[4 * q + 3]) * m);
        }
    }

    const float* x0 = x + (size_t)(b * LL) * CC * HWs + pix;   // feat[b][0]
    float f[CC];
#pragma unroll
    for (int c = 0; c < CC; ++c) f[c] = x0[(size_t)c * HWs] + agg[c];

#pragma unroll
    for (int d = 0; d < 8; ++d) {
        float s = bl[d];
        const float* wr = &wl[d * 32];
#pragma unroll
        for (int c = 0; c < CC; ++c) s = fmaf(f[c], wr[c], s);
        out[((size_t)b * CC + dg * 8 + d) * HWs + pix] = s;
    }
}

extern "C" void kernel_launch(void* const* d_in, const int* in_sizes, int n_in,
                              void* d_out, int out_size, void* d_ws, size_t ws_size,
                              hipStream_t stream)
{
    (void)in_sizes; (void)n_in; (void)out_size; (void)ws_size;
    const float* x     = (const float*)d_in[0];
    // d_in[1] = record_len (unused by reference)
    const float* M     = (const float*)d_in[2];
    const float* msg_w = (const float*)d_in[3];
    const float* msg_b = (const float*)d_in[4];
    const float* mlp_w = (const float*)d_in[5];
    const float* mlp_b = (const float*)d_in[6];
    float* out = (float*)d_out;

    float* ws      = (float*)d_ws;
    float* warped  = ws;                               // BL*C*HW floats, layout [bj][c][pix]
    float* msgpart = warped + (size_t)BL * CC * HWs;   // BL*HW*C floats, layout [bj][pix][c]
    float* econv   = msgpart + (size_t)BL * CC * HWs;  // BB*HW*C floats, layout [b][pix][c]

    {
        dim3 g(HWs / 256, BL, 4);           // 8448/256 = 33 exact
        k_warp<<<g, 256, 0, stream>>>(x, M, warped);
    }
    {
        dim3 g((HWs + 256 * PPT - 1) / (256 * PPT), BL + BB, 4);   // (9, 12, 4)
        k_conv<<<g, 256, 0, stream>>>(x, warped, msg_w, msgpart, econv);
    }
    {
        dim3 g(HWs / 256, BB, 4);
        k_combine<<<g, 256, 0, stream>>>(x, M, msgpart, econv, msg_b, mlp_w, mlp_b, out);
    }
}

// Round 3
// 46.624 us; speedup vs baseline: 6.2140x; 1.8854x over previous
//
#include <hip/hip_runtime.h>
#include <hip/hip_bf16.h>
#include <math.h>

// B=2, L=5, C=32, H=48, W=176, NUM_ITER=1.
// Algebraic cuts (validated R1): only i=0 slice matters; conv = warped-half (per j)
// + ego-half (per b, shared over j).
// R3: conv as tap-wise implicit GEMM on MFMA bf16 (fp32 accum). Channels-last bf16
// activations; weights packed [half][tap][oc][ic].
#define BB 2
#define LL 5
#define CC 32
#define HH 48
#define WW 176
#define HWs (HH * WW)          // 8448
#define BL (BB * LL)           // 10

typedef __attribute__((ext_vector_type(8))) short bf16x8;
typedef __attribute__((ext_vector_type(4))) float f32x4;

__device__ __forceinline__ unsigned short f2bf(float v) {
    __hip_bfloat16 h = __float2bfloat16(v);   // RNE
    return *reinterpret_cast<unsigned short*>(&h);
}

// ---- bilinear weights/indices for grid_sample(align_corners=False, zeros pad) ----
__device__ __forceinline__ void bilin_weights(const float* __restrict__ Mp, int h, int w,
                                              int& o00, int& o10, int& o01, int& o11,
                                              float& a00, float& a10, float& a01, float& a11)
{
    float xs = (2.0f * (float)w + 1.0f) / (float)WW - 1.0f;
    float ys = (2.0f * (float)h + 1.0f) / (float)HH - 1.0f;
    float gx = Mp[0] * xs + Mp[1] * ys + Mp[2];
    float gy = Mp[3] * xs + Mp[4] * ys + Mp[5];
    float ix = ((gx + 1.0f) * (float)WW - 1.0f) * 0.5f;
    float iy = ((gy + 1.0f) * (float)HH - 1.0f) * 0.5f;
    float x0f = floorf(ix), y0f = floorf(iy);
    float wx = ix - x0f, wy = iy - y0f;
    float x1f = x0f + 1.0f, y1f = y0f + 1.0f;
    bool vx0 = (x0f >= 0.0f) && (x0f <= (float)(WW - 1));
    bool vx1 = (x1f >= 0.0f) && (x1f <= (float)(WW - 1));
    bool vy0 = (y0f >= 0.0f) && (y0f <= (float)(HH - 1));
    bool vy1 = (y1f >= 0.0f) && (y1f <= (float)(HH - 1));
    int xi0 = (int)fminf(fmaxf(x0f, 0.0f), (float)(WW - 1));
    int xi1 = (int)fminf(fmaxf(x1f, 0.0f), (float)(WW - 1));
    int yi0 = (int)fminf(fmaxf(y0f, 0.0f), (float)(HH - 1));
    int yi1 = (int)fminf(fmaxf(y1f, 0.0f), (float)(HH - 1));
    o00 = yi0 * WW + xi0;
    o10 = yi0 * WW + xi1;
    o01 = yi1 * WW + xi0;
    o11 = yi1 * WW + xi1;
    a00 = (vx0 && vy0) ? (1.0f - wx) * (1.0f - wy) : 0.0f;
    a10 = (vx1 && vy0) ? wx * (1.0f - wy) : 0.0f;
    a01 = (vx0 && vy1) ? (1.0f - wx) * wy : 0.0f;
    a11 = (vx1 && vy1) ? wx * wy : 0.0f;
}

// ---- K0: pack msg_w[oc][64ic][3][3] fp32 -> Wp[half][tap][oc][ic] bf16 ----
__global__ __launch_bounds__(256) void k_wpack(const float* __restrict__ msg_w,
                                               unsigned short* __restrict__ Wp)
{
    int i = blockIdx.x * 256 + threadIdx.x;   // 2*9*32*32 = 18432
    if (i >= 2 * 9 * 32 * 32) return;
    int half = i / (9 * 32 * 32);
    int r    = i % (9 * 32 * 32);
    int tap  = r / (32 * 32);
    int r2   = r % (32 * 32);
    int oc   = r2 / 32;
    int ic   = r2 % 32;
    Wp[i] = f2bf(msg_w[(size_t)oc * 576 + (size_t)(half * 32 + ic) * 9 + tap]);
}

// ---- K1: warpedcl[bj][pix][c] (bf16) = bilinear warp; jobs 10,11 copy ego -> egocl ----
__global__ __launch_bounds__(256) void k_warp(const float* __restrict__ x,
                                              const float* __restrict__ M,
                                              unsigned short* __restrict__ warpedcl,
                                              unsigned short* __restrict__ egocl)
{
    int pix = blockIdx.x * 256 + threadIdx.x;
    if (pix >= HWs) return;
    int bj = blockIdx.y;
    int cg = blockIdx.z;      // 8 channels per thread

    bf16x8 v8;
    unsigned short* dst;
    if (bj < BL) {
        int w = pix % WW, h = pix / WW;
        int b = bj / LL, j = bj % LL;
        const float* Mp = M + (size_t)(b * LL * LL + j) * 6;   // M[b][0][j]
        int o00, o10, o01, o11;
        float a00, a10, a01, a11;
        bilin_weights(Mp, h, w, o00, o10, o01, o11, a00, a10, a01, a11);
        const float* img = x + (size_t)bj * CC * HWs + (size_t)cg * 8 * HWs;
#pragma unroll
        for (int c = 0; c < 8; ++c) {
            const float* ip = img + (size_t)c * HWs;
            float v = a00 * ip[o00] + a10 * ip[o10] + a01 * ip[o01] + a11 * ip[o11];
            v8[c] = (short)f2bf(v);
        }
        dst = warpedcl + ((size_t)bj * HWs + pix) * CC + cg * 8;
    } else {
        int b = bj - BL;
        const float* img = x + (size_t)(b * LL) * CC * HWs + (size_t)cg * 8 * HWs;
#pragma unroll
        for (int c = 0; c < 8; ++c)
            v8[c] = (short)f2bf(img[(size_t)c * HWs + pix]);
        dst = egocl + ((size_t)b * HWs + pix) * CC + cg * 8;
    }
    *(bf16x8*)dst = v8;
}

// ---- K2: tap-wise implicit-GEMM conv via mfma_f32_16x16x32_bf16 ----
// jobs 0..9: warped half -> msgpart[job][pix][oc]; jobs 10,11: ego half -> econv[b][pix][oc]
__global__ __launch_bounds__(256) void k_mfma(const unsigned short* __restrict__ warpedcl,
                                              const unsigned short* __restrict__ egocl,
                                              const unsigned short* __restrict__ Wp,
                                              float* __restrict__ msgpart,
                                              float* __restrict__ econv)
{
    int wave = threadIdx.x >> 6;
    int lane = threadIdx.x & 63;
    int lo   = lane & 15;        // A: row m / B: col n / D: col n
    int kblk = lane >> 4;        // k-block (8 bf16 each)

    int job = blockIdx.y;
    const unsigned short* A;
    const unsigned short* Wh;
    float* outp;
    if (job < BL) {
        A    = warpedcl + (size_t)job * HWs * CC;
        Wh   = Wp;                         // half 0
        outp = msgpart + (size_t)job * HWs * CC;
    } else {
        int b = job - BL;
        A    = egocl + (size_t)b * HWs * CC;
        Wh   = Wp + 9 * 32 * 32;           // half 1
        outp = econv + (size_t)b * HWs * CC;
    }

    int base = blockIdx.x * 128 + wave * 32;   // wave covers 32 pixels = 2 m-tiles
    int pf[2], ph[2], pw[2];
#pragma unroll
    for (int t = 0; t < 2; ++t) {
        pf[t] = base + t * 16 + lo;
        ph[t] = pf[t] / WW;
        pw[t] = pf[t] % WW;
    }

    f32x4 acc[2][2] = {};
    const bf16x8 zero = {0, 0, 0, 0, 0, 0, 0, 0};

#pragma unroll
    for (int tap = 0; tap < 9; ++tap) {
        const int dy = tap / 3 - 1, dx = tap % 3 - 1;
        bf16x8 Bf[2];
#pragma unroll
        for (int nt = 0; nt < 2; ++nt)
            Bf[nt] = *(const bf16x8*)(Wh + ((size_t)(tap * 32 + nt * 16 + lo) * 32 + kblk * 8));
#pragma unroll
        for (int t = 0; t < 2; ++t) {
            int hh = ph[t] + dy, wwp = pw[t] + dx;
            bool valid = (hh >= 0) && (hh < HH) && (wwp >= 0) && (wwp < WW);
            int ps = valid ? (pf[t] + dy * WW + dx) : pf[t];   // safe address
            bf16x8 Af = *(const bf16x8*)(A + (size_t)ps * CC + kblk * 8);
            if (!valid) Af = zero;
#pragma unroll
            for (int nt = 0; nt < 2; ++nt)
                acc[t][nt] = __builtin_amdgcn_mfma_f32_16x16x32_bf16(Af, Bf[nt], acc[t][nt], 0, 0, 0);
        }
    }

    // D: col(oc)=lane&15, row(pixel)=(lane>>4)*4+r
#pragma unroll
    for (int t = 0; t < 2; ++t)
#pragma unroll
        for (int nt = 0; nt < 2; ++nt)
#pragma unroll
            for (int r = 0; r < 4; ++r) {
                int pixel = base + t * 16 + kblk * 4 + r;
                outp[(size_t)pixel * CC + nt * 16 + lo] = acc[t][nt][r];
            }
}

// ---- K3: agg = max_j (msgpart_j + econv + bias) * mask_j ; out = mlp(x0 + agg); d split 4-way ----
__global__ __launch_bounds__(256) void k_combine(const float* __restrict__ x,
                                                 const float* __restrict__ M,
                                                 const float* __restrict__ msgpart,
                                                 const float* __restrict__ econv,
                                                 const float* __restrict__ msg_b,
                                                 const float* __restrict__ mlp_w,
                                                 const float* __restrict__ mlp_b,
                                                 float* __restrict__ out)
{
    __shared__ alignas(16) float wl[8 * 32];   // mlp_w rows dg*8..dg*8+7
    __shared__ float bl[8];
    __shared__ float mb[32];
    int b  = blockIdx.y;
    int dg = blockIdx.z;
    {
        int t = threadIdx.x;
        if (t < 256) wl[t] = mlp_w[(size_t)(dg * 8 + t / 32) * 32 + (t % 32)];
        if (t < 8)   bl[t] = mlp_b[dg * 8 + t];
        if (t < 32)  mb[t] = msg_b[t];
    }
    __syncthreads();

    int pix = blockIdx.x * 256 + threadIdx.x;
    if (pix >= HWs) return;
    int w = pix % WW, h = pix / WW;

    float ec[CC];
    {
        const float4* ep = (const float4*)(econv + ((size_t)b * HWs + pix) * CC);
#pragma unroll
        for (int q = 0; q < 8; ++q) {
            float4 v = ep[q];
            ec[4 * q + 0] = v.x + mb[4 * q + 0];
            ec[4 * q + 1] = v.y + mb[4 * q + 1];
            ec[4 * q + 2] = v.z + mb[4 * q + 2];
            ec[4 * q + 3] = v.w + mb[4 * q + 3];
        }
    }

    float agg[CC];
#pragma unroll
    for (int c = 0; c < CC; ++c) agg[c] = -INFINITY;

    for (int j = 0; j < LL; ++j) {
        const float* Mp = M + (size_t)(b * LL * LL + j) * 6;
        int o00, o10, o01, o11;
        float a00, a10, a01, a11;
        bilin_weights(Mp, h, w, o00, o10, o01, o11, a00, a10, a01, a11);
        float m = a00 + a10 + a01 + a11;   // grid_sample of ones image

        const float4* mp = (const float4*)(msgpart + ((size_t)(b * LL + j) * HWs + pix) * CC);
#pragma unroll
        for (int q = 0; q < 8; ++q) {
            float4 v = mp[q];
            agg[4 * q + 0] = fmaxf(agg[4 * q + 0], (v.x + ec[4 * q + 0]) * m);
            agg[4 * q + 1] = fmaxf(agg[4 * q + 1], (v.y + ec[4 * q + 1]) * m);
            agg[4 * q + 2] = fmaxf(agg[4 * q + 2], (v.z + ec[4 * q + 2]) * m);
            agg[4 * q + 3] = fmaxf(agg[4 * q + 3], (v.w + ec[4 * q + 3]) * m);
        }
    }

    const float* x0 = x + (size_t)(b * LL) * CC * HWs + pix;   // feat[b][0]
    float f[CC];
#pragma unroll
    for (int c = 0; c < CC; ++c) f[c] = x0[(size_t)c * HWs] + agg[c];

#pragma unroll
    for (int d = 0; d < 8; ++d) {
        float s = bl[d];
        const float* wr = &wl[d * 32];
#pragma unroll
        for (int c = 0; c < CC; ++c) s = fmaf(f[c], wr[c], s);
        out[((size_t)b * CC + dg * 8 + d) * HWs + pix] = s;
    }
}

extern "C" void kernel_launch(void* const* d_in, const int* in_sizes, int n_in,
                              void* d_out, int out_size, void* d_ws, size_t ws_size,
                              hipStream_t stream)
{
    (void)in_sizes; (void)n_in; (void)out_size; (void)ws_size;
    const float* x     = (const float*)d_in[0];
    // d_in[1] = record_len (unused by reference)
    const float* M     = (const float*)d_in[2];
    const float* msg_w = (const float*)d_in[3];
    const float* msg_b = (const float*)d_in[4];
    const float* mlp_w = (const float*)d_in[5];
    const float* mlp_b = (const float*)d_in[6];
    float* out = (float*)d_out;

    // workspace layout (16B-aligned segments)
    unsigned short* Wp       = (unsigned short*)d_ws;                   // 18432 bf16
    unsigned short* warpedcl = Wp + 2 * 9 * 32 * 32;                    // BL*HW*C bf16
    unsigned short* egocl    = warpedcl + (size_t)BL * HWs * CC;        // BB*HW*C bf16
    float*          msgpart  = (float*)(egocl + (size_t)BB * HWs * CC); // BL*HW*C f32
    float*          econv    = msgpart + (size_t)BL * HWs * CC;         // BB*HW*C f32

    {
        k_wpack<<<dim3(72), 256, 0, stream>>>(msg_w, Wp);
    }
    {
        dim3 g(HWs / 256, BL + BB, 4);   // (33, 12, 4)
        k_warp<<<g, 256, 0, stream>>>(x, M, warpedcl, egocl);
    }
    {
        dim3 g(HWs / 128, BL + BB);      // (66, 12)
        k_mfma<<<g, 256, 0, stream>>>(warpedcl, egocl, Wp, msgpart, econv);
    }
    {
        dim3 g(HWs / 256, BB, 4);        // (33, 2, 4)
        k_combine<<<g, 256, 0, stream>>>(x, M, msgpart, econv, msg_b, mlp_w, mlp_b, out);
    }
}

// Round 4
// 30.420 us; speedup vs baseline: 9.5241x; 1.5327x over previous
//
#include <hip/hip_runtime.h>
#include <hip/hip_bf16.h>
#include <math.h>

// B=2, L=5, C=32, H=48, W=176, NUM_ITER=1.
// Algebraic cuts (validated R1): only i=0 slice matters; conv = warped-half (per j)
// + ego-half (per b, shared over j).
// R3: conv as tap-wise implicit GEMM on MFMA bf16. R4: fused into 2 kernels;
// mask precomputed; mlp as second MFMA stage via same-wave LDS transpose.
#define BB 2
#define LL 5
#define CC 32
#define HH 48
#define WW 176
#define HWs (HH * WW)          // 8448
#define BL (BB * LL)           // 10

typedef __attribute__((ext_vector_type(8))) short bf16x8;
typedef __attribute__((ext_vector_type(4))) float f32x4;

__device__ __forceinline__ unsigned short f2bf(float v) {
    __hip_bfloat16 h = __float2bfloat16(v);   // RNE
    return *reinterpret_cast<unsigned short*>(&h);
}

// ---- bilinear weights/indices for grid_sample(align_corners=False, zeros pad) ----
__device__ __forceinline__ void bilin_weights(const float* __restrict__ Mp, int h, int w,
                                              int& o00, int& o10, int& o01, int& o11,
                                              float& a00, float& a10, float& a01, float& a11)
{
    float xs = (2.0f * (float)w + 1.0f) / (float)WW - 1.0f;
    float ys = (2.0f * (float)h + 1.0f) / (float)HH - 1.0f;
    float gx = Mp[0] * xs + Mp[1] * ys + Mp[2];
    float gy = Mp[3] * xs + Mp[4] * ys + Mp[5];
    float ix = ((gx + 1.0f) * (float)WW - 1.0f) * 0.5f;
    float iy = ((gy + 1.0f) * (float)HH - 1.0f) * 0.5f;
    float x0f = floorf(ix), y0f = floorf(iy);
    float wx = ix - x0f, wy = iy - y0f;
    float x1f = x0f + 1.0f, y1f = y0f + 1.0f;
    bool vx0 = (x0f >= 0.0f) && (x0f <= (float)(WW - 1));
    bool vx1 = (x1f >= 0.0f) && (x1f <= (float)(WW - 1));
    bool vy0 = (y0f >= 0.0f) && (y0f <= (float)(HH - 1));
    bool vy1 = (y1f >= 0.0f) && (y1f <= (float)(HH - 1));
    int xi0 = (int)fminf(fmaxf(x0f, 0.0f), (float)(WW - 1));
    int xi1 = (int)fminf(fmaxf(x1f, 0.0f), (float)(WW - 1));
    int yi0 = (int)fminf(fmaxf(y0f, 0.0f), (float)(HH - 1));
    int yi1 = (int)fminf(fmaxf(y1f, 0.0f), (float)(HH - 1));
    o00 = yi0 * WW + xi0;
    o10 = yi0 * WW + xi1;
    o01 = yi1 * WW + xi0;
    o11 = yi1 * WW + xi1;
    a00 = (vx0 && vy0) ? (1.0f - wx) * (1.0f - wy) : 0.0f;
    a10 = (vx1 && vy0) ? wx * (1.0f - wy) : 0.0f;
    a01 = (vx0 && vy1) ? (1.0f - wx) * wy : 0.0f;
    a11 = (vx1 && vy1) ? wx * wy : 0.0f;
}

// ---- K_prep: y<10: warp -> warpedcl (bf16 CL) + mask (z==0);
//              y=10,11: ego -> egocl (bf16 CL) + x0cl (f32 CL);
//              y=12: pack msg_w -> Wp [half][tap][oc][ic] bf16, mlp_w -> Wp2 [d][c] bf16
__global__ __launch_bounds__(256) void k_prep(const float* __restrict__ x,
                                              const float* __restrict__ M,
                                              const float* __restrict__ msg_w,
                                              const float* __restrict__ mlp_w,
                                              unsigned short* __restrict__ warpedcl,
                                              unsigned short* __restrict__ egocl,
                                              float* __restrict__ x0cl,
                                              float* __restrict__ maskb,
                                              unsigned short* __restrict__ Wp,
                                              unsigned short* __restrict__ Wp2)
{
    int y = blockIdx.y;
    if (y < BL) {
        int pix = blockIdx.x * 256 + threadIdx.x;
        int cg  = blockIdx.z;
        int w = pix % WW, h = pix / WW;
        int b = y / LL, j = y % LL;
        const float* Mp = M + (size_t)(b * LL * LL + j) * 6;   // M[b][0][j]
        int o00, o10, o01, o11;
        float a00, a10, a01, a11;
        bilin_weights(Mp, h, w, o00, o10, o01, o11, a00, a10, a01, a11);
        if (cg == 0)
            maskb[(size_t)y * HWs + pix] = a00 + a10 + a01 + a11;
        const float* img = x + (size_t)y * CC * HWs + (size_t)cg * 8 * HWs;
        bf16x8 v8;
#pragma unroll
        for (int c = 0; c < 8; ++c) {
            const float* ip = img + (size_t)c * HWs;
            float v = a00 * ip[o00] + a10 * ip[o10] + a01 * ip[o01] + a11 * ip[o11];
            v8[c] = (short)f2bf(v);
        }
        *(bf16x8*)(warpedcl + ((size_t)y * HWs + pix) * CC + cg * 8) = v8;
    } else if (y < BL + BB) {
        int b = y - BL;
        int pix = blockIdx.x * 256 + threadIdx.x;
        int cg  = blockIdx.z;
        const float* img = x + (size_t)(b * LL) * CC * HWs + (size_t)cg * 8 * HWs;
        float v[8];
        bf16x8 v8;
#pragma unroll
        for (int c = 0; c < 8; ++c) {
            v[c] = img[(size_t)c * HWs + pix];
            v8[c] = (short)f2bf(v[c]);
        }
        *(bf16x8*)(egocl + ((size_t)b * HWs + pix) * CC + cg * 8) = v8;
        float* xp = x0cl + ((size_t)b * HWs + pix) * CC + cg * 8;
        *(float4*)xp       = make_float4(v[0], v[1], v[2], v[3]);
        *(float4*)(xp + 4) = make_float4(v[4], v[5], v[6], v[7]);
    } else {
        int i = (blockIdx.z * gridDim.x + blockIdx.x) * 256 + threadIdx.x;
        if (i < 2 * 9 * 32 * 32) {
            int half = i / (9 * 32 * 32);
            int r    = i % (9 * 32 * 32);
            int tap  = r / (32 * 32);
            int r2   = r % (32 * 32);
            int oc   = r2 / 32;
            int ic   = r2 % 32;
            Wp[i] = f2bf(msg_w[(size_t)oc * 576 + (size_t)(half * 32 + ic) * 9 + tap]);
        } else if (i < 2 * 9 * 32 * 32 + 32 * 32) {
            int k = i - 2 * 9 * 32 * 32;
            Wp2[k] = f2bf(mlp_w[k]);     // [d][c] row-major, as stored
        }
    }
}

// ---- K_fused: per-wave 16-pixel tile; 6 half-convs (MFMA) + bias + mask*max + x0 skip
//      + mlp via second MFMA (LDS transpose, same-wave, no barrier) ----
__global__ __launch_bounds__(256) void k_fused(const unsigned short* __restrict__ warpedcl,
                                               const unsigned short* __restrict__ egocl,
                                               const float* __restrict__ x0cl,
                                               const float* __restrict__ maskb,
                                               const unsigned short* __restrict__ Wp,
                                               const unsigned short* __restrict__ Wp2,
                                               const float* __restrict__ msg_b,
                                               const float* __restrict__ mlp_b,
                                               float* __restrict__ out)
{
    __shared__ float fl[64][33];            // per-wave 16 rows; padded (2-way max conflicts)
    int wv   = threadIdx.x >> 6;
    int lane = threadIdx.x & 63;
    int lo   = lane & 15;
    int kblk = lane >> 4;
    int b    = blockIdx.y;
    int p0   = blockIdx.x * 64 + wv * 16;   // wave's 16 pixels
    int pf   = p0 + lo;
    int ph   = pf / WW, pw = pf % WW;

    // hoist tap addressing: safe pixel index + validity bit per tap
    int ps[9];
    unsigned vbits = 0;
#pragma unroll
    for (int tap = 0; tap < 9; ++tap) {
        int dy = tap / 3 - 1, dx = tap % 3 - 1;
        int hh = ph + dy, wwp = pw + dx;
        bool valid = (hh >= 0) && (hh < HH) && (wwp >= 0) && (wwp < WW);
        ps[tap] = valid ? (pf + dy * WW + dx) : pf;
        vbits |= (valid ? 1u : 0u) << tap;
    }
    const bf16x8 zero = {0, 0, 0, 0, 0, 0, 0, 0};

    // preload warped-half B fragments (reused across 5 j)
    bf16x8 Bw[9][2];
#pragma unroll
    for (int tap = 0; tap < 9; ++tap)
#pragma unroll
        for (int nt = 0; nt < 2; ++nt)
            Bw[tap][nt] = *(const bf16x8*)(Wp + ((size_t)(tap * 32 + nt * 16 + lo) * 32 + kblk * 8));

    // ego half-conv (+ conv bias folded in)
    f32x4 acce[2] = {};
    {
        const unsigned short* Ae = egocl + (size_t)b * HWs * CC;
#pragma unroll
        for (int tap = 0; tap < 9; ++tap) {
            bf16x8 Af = *(const bf16x8*)(Ae + (size_t)ps[tap] * CC + kblk * 8);
            if (!((vbits >> tap) & 1)) Af = zero;
#pragma unroll
            for (int nt = 0; nt < 2; ++nt) {
                bf16x8 Bf = *(const bf16x8*)(Wp + 9 * 32 * 32 + ((size_t)(tap * 32 + nt * 16 + lo) * 32 + kblk * 8));
                acce[nt] = __builtin_amdgcn_mfma_f32_16x16x32_bf16(Af, Bf, acce[nt], 0, 0, 0);
            }
        }
        float b0 = msg_b[lo], b1 = msg_b[16 + lo];
#pragma unroll
        for (int r = 0; r < 4; ++r) { acce[0][r] += b0; acce[1][r] += b1; }
    }

    // j-loop: warped half-conv, add ego+bias, mask, running max
    f32x4 agg[2];
#pragma unroll
    for (int r = 0; r < 4; ++r) { agg[0][r] = -INFINITY; agg[1][r] = -INFINITY; }

    for (int j = 0; j < LL; ++j) {
        const unsigned short* Aw = warpedcl + (size_t)(b * LL + j) * HWs * CC;
        f32x4 acc[2] = {};
#pragma unroll
        for (int tap = 0; tap < 9; ++tap) {
            bf16x8 Af = *(const bf16x8*)(Aw + (size_t)ps[tap] * CC + kblk * 8);
            if (!((vbits >> tap) & 1)) Af = zero;
#pragma unroll
            for (int nt = 0; nt < 2; ++nt)
                acc[nt] = __builtin_amdgcn_mfma_f32_16x16x32_bf16(Af, Bw[tap][nt], acc[nt], 0, 0, 0);
        }
        float4 mk = *(const float4*)(maskb + (size_t)(b * LL + j) * HWs + p0 + kblk * 4);
        float mkr[4] = {mk.x, mk.y, mk.z, mk.w};
#pragma unroll
        for (int nt = 0; nt < 2; ++nt)
#pragma unroll
            for (int r = 0; r < 4; ++r)
                agg[nt][r] = fmaxf(agg[nt][r], (acc[nt][r] + acce[nt][r]) * mkr[r]);
    }

    // f = x0 + agg -> LDS transpose (D-layout rows: pixel = kblk*4+r, col c = nt*16+lo)
#pragma unroll
    for (int nt = 0; nt < 2; ++nt)
#pragma unroll
        for (int r = 0; r < 4; ++r) {
            int pixl = kblk * 4 + r;
            float f = agg[nt][r] + x0cl[((size_t)b * HWs + p0 + pixl) * CC + nt * 16 + lo];
            fl[wv * 16 + pixl][nt * 16 + lo] = f;
        }
    // same-wave LDS read-back (compiler inserts lgkmcnt; no cross-wave sharing)

    // mlp: A = f[pix][c] (m=lo pixel, k=c), B = Wp2[d][c] (n=d, k=c)
    bf16x8 Afm;
#pragma unroll
    for (int e = 0; e < 8; ++e)
        Afm[e] = (short)f2bf(fl[wv * 16 + lo][kblk * 8 + e]);

#pragma unroll
    for (int nt2 = 0; nt2 < 2; ++nt2) {
        bf16x8 Bm = *(const bf16x8*)(Wp2 + ((size_t)(nt2 * 16 + lo) * 32 + kblk * 8));
        f32x4 om = {};
        om = __builtin_amdgcn_mfma_f32_16x16x32_bf16(Afm, Bm, om, 0, 0, 0);
        float mb2 = mlp_b[nt2 * 16 + lo];
        int d = nt2 * 16 + lo;
#pragma unroll
        for (int r = 0; r < 4; ++r)
            out[((size_t)b * CC + d) * HWs + p0 + kblk * 4 + r] = om[r] + mb2;
    }
}

extern "C" void kernel_launch(void* const* d_in, const int* in_sizes, int n_in,
                              void* d_out, int out_size, void* d_ws, size_t ws_size,
                              hipStream_t stream)
{
    (void)in_sizes; (void)n_in; (void)out_size; (void)ws_size;
    const float* x     = (const float*)d_in[0];
    // d_in[1] = record_len (unused by reference)
    const float* M     = (const float*)d_in[2];
    const float* msg_w = (const float*)d_in[3];
    const float* msg_b = (const float*)d_in[4];
    const float* mlp_w = (const float*)d_in[5];
    const float* mlp_b = (const float*)d_in[6];
    float* out = (float*)d_out;

    // workspace layout (all segments 16B-aligned)
    unsigned short* Wp       = (unsigned short*)d_ws;                    // 18432 bf16
    unsigned short* Wp2      = Wp + 2 * 9 * 32 * 32;                     // 1024 bf16
    unsigned short* warpedcl = Wp2 + 32 * 32;                            // BL*HW*C bf16
    unsigned short* egocl    = warpedcl + (size_t)BL * HWs * CC;         // BB*HW*C bf16
    float*          x0cl     = (float*)(egocl + (size_t)BB * HWs * CC);  // BB*HW*C f32
    float*          maskb    = x0cl + (size_t)BB * HWs * CC;             // BL*HW f32

    {
        dim3 g(HWs / 256, BL + BB + 1, 4);   // (33, 13, 4)
        k_prep<<<g, 256, 0, stream>>>(x, M, msg_w, mlp_w,
                                      warpedcl, egocl, x0cl, maskb, Wp, Wp2);
    }
    {
        dim3 g(HWs / 64, BB);                // (132, 2)
        k_fused<<<g, 256, 0, stream>>>(warpedcl, egocl, x0cl, maskb, Wp, Wp2,
                                       msg_b, mlp_b, out);
    }
}